// Round 4
// baseline (565.907 us; speedup 1.0000x reference)
//
#include <hip/hip_runtime.h>
#include <cstdint>

#define B_ 8
#define T_ 4096
#define TP1 4097
#define IN_ 512
#define H_ 512
#define N3H 1536
#define KD 1024
#define CHUNKS 64
#define CLEN 64   // T_/CHUNKS
#define NT 16     // KD/64 K-tiles

typedef __attribute__((ext_vector_type(4))) float floatx4;
typedef __attribute__((ext_vector_type(4))) float f4;
typedef __attribute__((ext_vector_type(8))) short short8;
typedef __attribute__((ext_vector_type(4))) unsigned short us4;
typedef __attribute__((ext_vector_type(4))) _Float16 h4;

__device__ __forceinline__ unsigned short f2bf(float v){
  unsigned int u = __float_as_uint(v);
  unsigned int r = (u + 0x7fffu + ((u >> 16) & 1u)) >> 16;
  return (unsigned short)r;
}
// fast sigmoid: one v_exp_f32 + one v_rcp_f32 (no IEEE div sequence)
__device__ __forceinline__ float sigm(float x){
  return __builtin_amdgcn_rcpf(1.f + __expf(-x));
}
__device__ __forceinline__ float tanhf_(float x){ return 2.f*sigm(2.f*x) - 1.f; }

#define GLLS(src, dst) __builtin_amdgcn_global_load_lds( \
    (const __attribute__((address_space(1))) void*)(src), \
    (__attribute__((address_space(3))) void*)(dst), 16, 0, 0)

// x f32 [B,T,IN] -> xpad bf16 [B, T+1, IN] with zero row at t'=0 (causal pad)
__global__ void cast_pad_kernel(const float* __restrict__ x, unsigned short* __restrict__ xpad){
  int64_t i = (int64_t)blockIdx.x*256 + threadIdx.x;       // over B*TP1*(IN/4)
  const int64_t total = (int64_t)B_*TP1*(IN_/4);
  if (i >= total) return;
  int cg = (int)(i & 127);
  int64_t r = i >> 7;                                      // row (b*TP1 + t)
  int t = (int)(r % TP1);
  int b = (int)(r / TP1);
  us4 o;
  if (t == 0){ o = (us4){0,0,0,0}; }
  else {
    f4 v = *(const f4*)(x + ((int64_t)b*T_ + (t-1))*IN_ + cg*4);
    #pragma unroll
    for (int u=0;u<4;++u) o[u] = f2bf(v[u]);
  }
  *(us4*)(xpad + r*IN_ + cg*4) = o;
}

// w f32 [3H, IN, K=2] -> wt bf16 [3H, 1024], k-major halves; blockIdx.y picks layer
__global__ void wt_kernel(const float* __restrict__ wA, unsigned short* __restrict__ wtA,
                          const float* __restrict__ wB, unsigned short* __restrict__ wtB){
  int i = blockIdx.x*256 + threadIdx.x;                    // over N3H*512
  if (i >= N3H*512) return;
  const float* w = blockIdx.y ? wB : wA;
  unsigned short* wt = blockIdx.y ? wtB : wtA;
  int ci = i & 511;
  int o = i >> 9;
  const float* wp = w + (int64_t)o*KD + ci*2;
  wt[(int64_t)o*KD + ci]       = f2bf(wp[0]);
  wt[(int64_t)o*KD + 512 + ci] = f2bf(wp[1]);
}

// ---------------------------------------------------------------------------
// PERSISTENT 256x256x64 8-phase GEMM (verified R1 schedule, 16x16x32 MFMA).
// 256 blocks (1/CU); block p chains 3 output tiles: same mt (A-panel reuse),
// nt = mhalf*3 + {0,1,2}. During tiles NT-2/NT-1 of macro i the stage slots
// prefetch macro i+1's K-tiles 0/1 (A identical across macros; B advances by
// 256*KD). Buffer parity continuous (NT even); vmcnt(4) steady-state carries
// across the boundary; only the last macro drains. Epilogue overlaps the
// in-flight prefetch.
// LDS (shorts): A: d*16384 + h*8192 + row*64 + physSlot*8 ; B: +32768.
//   physSlot = logicalSlot ^ (row&7); GLLS writes linearly, swizzle applied by
//   pre-permuting the per-lane GLOBAL source slot (lcol ^ lrow).
// ---------------------------------------------------------------------------
#define MFMA(a,b,c) __builtin_amdgcn_mfma_f32_16x16x32_bf16(a,b,c,0,0,0)
#define BAR() __builtin_amdgcn_s_barrier()

#define ST_A(tt, h) do { \
    const unsigned short* _s = aSrc + (h)*128*IN_ + ((tt)&(NT-1))*64; \
    unsigned short* _d = smem + ((tt)&1)*16384 + (h)*8192 + dstBase; \
    GLLS(_s, _d); GLLS(_s + 64*IN_, _d + 4096); } while(0)
#define ST_BX(PTR, tt, h) do { \
    const unsigned short* _s = (PTR) + (h)*128*KD + ((tt)&(NT-1))*64; \
    unsigned short* _d = smem + 32768 + ((tt)&1)*16384 + (h)*8192 + dstBase; \
    GLLS(_s, _d); GLLS(_s + 64*KD, _d + 4096); } while(0)
#define ST_B(tt, h) ST_BX(bSrcC, tt, h)

#define LDA(d,h,i,s) (*(const short8*)(smem + (d)*16384 + (h)*8192 + aRd + (i)*1024 + (s)))
#define LDB(d,h,i,s) (*(const short8*)(smem + (d)*16384 + (h)*8192 + bRd + (i)*1024 + (s)))

// S0..S3: stage statements for phases q0..q3 (pass (void)0 for none)
#define TILE(tc, S0, S1, S2, S3, VMN) do { \
  const int d_ = (tc) & 1; \
  /* q0: read A-half0 (m0..3) + B-half0 (n0..1) */ \
  _Pragma("unroll") for (int i=0;i<4;++i){ aF[i][0]=LDA(d_,0,i,sw0); aF[i][1]=LDA(d_,0,i,sw1); } \
  _Pragma("unroll") for (int j=0;j<2;++j){ bF0[j][0]=LDB(d_,0,j,sw0); bF0[j][1]=LDB(d_,0,j,sw1); } \
  S0; \
  BAR(); \
  __builtin_amdgcn_s_setprio(1); \
  _Pragma("unroll") for (int i=0;i<4;++i) _Pragma("unroll") for (int j=0;j<2;++j){ \
    acc[i][j]=MFMA(aF[i][0],bF0[j][0],acc[i][j]); acc[i][j]=MFMA(aF[i][1],bF0[j][1],acc[i][j]); } \
  __builtin_amdgcn_s_setprio(0); \
  BAR(); \
  /* q1: read B-half1 (n2..3) */ \
  _Pragma("unroll") for (int j=0;j<2;++j){ bF1[j][0]=LDB(d_,1,j,sw0); bF1[j][1]=LDB(d_,1,j,sw1); } \
  S1; \
  BAR(); \
  __builtin_amdgcn_s_setprio(1); \
  _Pragma("unroll") for (int i=0;i<4;++i) _Pragma("unroll") for (int j=0;j<2;++j){ \
    acc[i][2+j]=MFMA(aF[i][0],bF1[j][0],acc[i][2+j]); acc[i][2+j]=MFMA(aF[i][1],bF1[j][1],acc[i][2+j]); } \
  __builtin_amdgcn_s_setprio(0); \
  BAR(); \
  /* q2: read A-half1 (m4..7) */ \
  _Pragma("unroll") for (int i=0;i<4;++i){ aF[i][0]=LDA(d_,1,i,sw0); aF[i][1]=LDA(d_,1,i,sw1); } \
  S2; \
  BAR(); \
  __builtin_amdgcn_s_setprio(1); \
  _Pragma("unroll") for (int i=0;i<4;++i) _Pragma("unroll") for (int j=0;j<2;++j){ \
    acc[4+i][j]=MFMA(aF[i][0],bF0[j][0],acc[4+i][j]); acc[4+i][j]=MFMA(aF[i][1],bF0[j][1],acc[4+i][j]); } \
  __builtin_amdgcn_s_setprio(0); \
  BAR(); \
  /* q3 */ \
  S3; \
  BAR(); \
  __builtin_amdgcn_s_setprio(1); \
  _Pragma("unroll") for (int i=0;i<4;++i) _Pragma("unroll") for (int j=0;j<2;++j){ \
    acc[4+i][2+j]=MFMA(aF[i][0],bF1[j][0],acc[4+i][2+j]); acc[4+i][2+j]=MFMA(aF[i][1],bF1[j][1],acc[4+i][2+j]); } \
  __builtin_amdgcn_s_setprio(0); \
  if ((VMN)==4) asm volatile("s_waitcnt vmcnt(4)" ::: "memory"); \
  else if ((VMN)==0) asm volatile("s_waitcnt vmcnt(0)" ::: "memory"); \
  BAR(); \
} while(0)

__global__ __launch_bounds__(512, 2) void gemm_kernel(
    const unsigned short* __restrict__ A, const unsigned short* __restrict__ W,
    const float* __restrict__ bias, _Float16* __restrict__ C){
  __shared__ unsigned short smem[65536];   // 128 KiB: A [0,32768), B [32768,65536)
  const int tid  = threadIdx.x;
  const int lane = tid & 63;
  const int wave = tid >> 6;
  const int l16  = lane & 15;
  const int quad = lane >> 4;
  const int wm = wave >> 2;      // 0..1 (M)
  const int wn = wave & 3;       // 0..3 (N)
  const int lrow = lane >> 3;    // 0..7
  const int lcol = lane & 7;     // 0..7

  // persistent mapping: p bijective XCD-chunked over 256 blocks (= 8 xcd * 32)
  const int bid = blockIdx.x;
  const int p = (bid & 7) * 32 + (bid >> 3);
  const int mt = p >> 1;                 // 0..127
  const int mhalf = p & 1;               // nt group: mhalf*3 + mi
  const int m0 = mt * 256;
  const int bb = m0 / T_;                // tile fully inside one batch (256 | 4096)

  // staging: lane writes LDS linearly (row = wave*8+lrow, slot = lcol);
  // source slot pre-swizzled so LDS physSlot q holds logical q^(row&7)
  const unsigned short* aSrc = A + (int64_t)(m0 + bb + wave*8 + lrow)*IN_ + (lcol ^ lrow)*8;
  const unsigned short* bSrcC = W + (int64_t)(mhalf*3*256 + wave*8 + lrow)*KD + (lcol ^ lrow)*8;
  const int dstBase = (wave*8 + lrow)*64 + lcol*8;   // shorts; == lane*16B per wave

  // ds_read bases (shorts); fragment row&7 == l16&7
  const int sw0 = ( quad      ^ (l16 & 7)) * 8;      // k-substep s=0
  const int sw1 = ((4 ^ quad) ^ (l16 & 7)) * 8;      // k-substep s=1
  const int aRd = (wm*64 + l16)*64;
  const int bRd = 32768 + (wn*32 + l16)*64;

  floatx4 acc[8][4];
  short8 aF[4][2], bF0[2][2], bF1[2][2];

  // prologue: macro0 tile0 {A0,B0,A1,B1} + tile1 {A0,B0}; 2 half-tiles in flight
  ST_A(0,0); ST_B(0,0); ST_A(0,1); ST_B(0,1); ST_A(1,0); ST_B(1,0);
  asm volatile("s_waitcnt vmcnt(4)" ::: "memory");
  BAR();

  for (int mi = 0; mi < 3; ++mi){
    #pragma unroll
    for (int i=0;i<8;i++)
      #pragma unroll
      for (int j=0;j<4;j++) acc[i][j] = (floatx4){0.f,0.f,0.f,0.f};

    const unsigned short* bSrcN = bSrcC + (int64_t)256*KD;

    #pragma unroll 2
    for (int t = 0; t < NT-2; ++t)
      TILE(t, ST_A(t+1,1), ST_B(t+1,1), ST_A(t+2,0), ST_B(t+2,0), 4);

    if (mi < 2){
      // boundary: keep steady-state; stage next macro's K-tiles 0/1
      TILE(NT-2, ST_A(NT-1,1), ST_B(NT-1,1), ST_A(NT,0),   ST_BX(bSrcN,NT,0),   4);
      TILE(NT-1, ST_A(NT,1),   ST_BX(bSrcN,NT,1), ST_A(NT+1,0), ST_BX(bSrcN,NT+1,0), 4);
    } else {
      TILE(NT-2, ST_A(NT-1,1), ST_B(NT-1,1), (void)0, (void)0, 0);
      TILE(NT-1, (void)0, (void)0, (void)0, (void)0, -1);
    }

    // epilogue for this macro (overlaps in-flight prefetch for mi<2)
    const int n0 = (mhalf*3 + mi) * 256;
    const int act = n0 >> 9;              // 0=z(tanh), 1=f(sigm), 2=o(sigm)
    float bv[4];
    #pragma unroll
    for (int n=0;n<4;++n){
      const int cb = ((n&2)?128:0) + wn*32 + (n&1)*16;
      bv[n] = bias[n0 + cb + l16];
    }
    #pragma unroll
    for (int m=0;m<8;++m){
      const int rb = ((m&4)?128:0) + wm*64 + (m&3)*16;
      const int row = m0 + rb + quad*4;
      #pragma unroll
      for (int n=0;n<4;++n){
        const int cb = ((n&2)?128:0) + wn*32 + (n&1)*16;
        const int col = n0 + cb + l16;
        _Float16* cp = C + (int64_t)row*N3H + col;
        #pragma unroll
        for (int r=0;r<4;++r){
          float v = acc[m][n][r] + bv[n];
          v = (act == 0) ? tanhf_(v) : sigm(v);
          cp[(int64_t)r*N3H] = (_Float16)v;
        }
      }
    }
    bSrcC = bSrcN;
  }
}

// phase 1: per-chunk affine composition (Aa, Bb): h_out = Aa*h_in + Bb
__global__ void scan_phase1(const _Float16* __restrict__ conv,
                            float* __restrict__ carA, float* __restrict__ carB){
  int q = blockIdx.x*256 + threadIdx.x;     // CHUNKS*8*128 = 65536
  int chg = q & 127;
  int bq = (q >> 7) & 7;
  int c  = q >> 10;
  int ch = chg*4;
  f4 Aa = {1.f,1.f,1.f,1.f}, Bb = {0.f,0.f,0.f,0.f};
  const _Float16* p = conv + ((int64_t)bq*T_ + c*CLEN)*N3H + ch;
  for (int g=0; g<CLEN/8; ++g){
    h4 zb[8], fb[8];
    #pragma unroll
    for (int u=0;u<8;++u){
      zb[u] = *(const h4*)(p + (int64_t)u*N3H);
      fb[u] = *(const h4*)(p + (int64_t)u*N3H + 512);
    }
    #pragma unroll
    for (int u=0;u<8;++u){
      #pragma unroll
      for (int v=0;v<4;++v){
        float fv = (float)fb[u][v];
        float zv = (float)zb[u][v];
        Aa[v] *= fv;
        Bb[v] = fv*Bb[v] + (1.f-fv)*zv;
      }
    }
    p += (int64_t)8*N3H;
  }
  *(f4*)(carA + (int64_t)q*4) = Aa;
  *(f4*)(carB + (int64_t)q*4) = Bb;
}

// phase 2: scan over chunks; emit h at chunk starts + final hT. 1 channel/thread.
__global__ void scan_phase2(const float* __restrict__ carA, const float* __restrict__ carB,
                            float* __restrict__ hstart, float* __restrict__ hT){
  int q = blockIdx.x*256 + threadIdx.x;     // 4096 channels (b*512+ch)
  float h = 0.f;
  for (int c=0;c<CHUNKS;++c){
    int64_t idx = (int64_t)c*4096 + q;
    hstart[idx] = h;
    h = carA[idx]*h + carB[idx];
  }
  hT[q] = h;
}

// phase 3: replay chunk with true h-start, apply o*h, write output
template<int LAYER>
__global__ void scan_phase3(const _Float16* __restrict__ conv,
                            const float* __restrict__ hstart, unsigned short* __restrict__ xpad,
                            float* __restrict__ outf){
  int q = blockIdx.x*256 + threadIdx.x;     // 65536
  int chg = q & 127;
  int bq = (q >> 7) & 7;
  int c  = q >> 10;
  int ch = chg*4;
  f4 h;
  #pragma unroll
  for (int v=0;v<4;++v) h[v] = hstart[(int64_t)c*4096 + bq*512 + ch + v];
  const _Float16* p = conv + ((int64_t)bq*T_ + c*CLEN)*N3H + ch;
  int t = c*CLEN;
  for (int g=0; g<CLEN/8; ++g){
    h4 zb[8], fb[8], ob[8];
    #pragma unroll
    for (int u=0;u<8;++u){
      zb[u] = *(const h4*)(p + (int64_t)u*N3H);
      fb[u] = *(const h4*)(p + (int64_t)u*N3H + 512);
      ob[u] = *(const h4*)(p + (int64_t)u*N3H + 1024);
    }
    #pragma unroll
    for (int u=0;u<8;++u){
      if (LAYER == 0){
        us4 ov4;
        #pragma unroll
        for (int v=0;v<4;++v){
          float fv = (float)fb[u][v];
          h[v] = fv*h[v] + (1.f-fv)*(float)zb[u][v];
          ov4[v] = f2bf((float)ob[u][v]*h[v]);
        }
        *(us4*)(xpad + ((int64_t)bq*TP1 + t+u + 1)*IN_ + ch) = ov4;
      } else {
        f4 of4;
        #pragma unroll
        for (int v=0;v<4;++v){
          float fv = (float)fb[u][v];
          h[v] = fv*h[v] + (1.f-fv)*(float)zb[u][v];
          of4[v] = (float)ob[u][v]*h[v];
        }
        *(f4*)(outf + ((int64_t)bq*T_ + t+u)*H_ + ch) = of4;
      }
    }
    t += 8; p += (int64_t)8*N3H;
  }
}

extern "C" void kernel_launch(void* const* d_in, const int* in_sizes, int n_in,
                              void* d_out, int out_size, void* d_ws, size_t ws_size,
                              hipStream_t stream){
  const float* x  = (const float*)d_in[0];
  const float* w0 = (const float*)d_in[1];
  const float* b0 = (const float*)d_in[2];
  const float* w1 = (const float*)d_in[3];
  const float* b1 = (const float*)d_in[4];
  float* out = (float*)d_out;

  char* ws = (char*)d_ws;
  size_t off = 0;
  auto alloc = [&](size_t bytes)->char*{
    char* p = ws + off; off = (off + bytes + 255) & ~(size_t)255; return p; };
  unsigned short* xpad = (unsigned short*)alloc((size_t)B_*TP1*IN_*2);
  unsigned short* Wt0  = (unsigned short*)alloc((size_t)N3H*KD*2);
  unsigned short* Wt1  = (unsigned short*)alloc((size_t)N3H*KD*2);
  _Float16* conv = (_Float16*)alloc((size_t)B_*T_*N3H*2);
  float* carA = (float*)alloc((size_t)CHUNKS*4096*4);
  float* carB = (float*)alloc((size_t)CHUNKS*4096*4);
  float* hst  = (float*)alloc((size_t)CHUNKS*4096*4);
  if (off > ws_size) return;  // workspace too small -> fail loudly in validation

  float* out_main = out;
  float* h0 = out + (int64_t)B_*T_*H_;
  float* h1 = h0 + B_*H_;

  const int64_t padN = (int64_t)B_*TP1*(IN_/4);
  cast_pad_kernel<<<(int)((padN + 255)/256), 256, 0, stream>>>(x, xpad);
  dim3 wgrid((N3H*512 + 255)/256, 2);
  wt_kernel<<<wgrid, 256, 0, stream>>>(w0, Wt0, w1, Wt1);

  const int ggrid = 256;                         // persistent: 1 block/CU, 3 tiles each
  const int sgrid = (CHUNKS*8*128) / 256;        // 256
  gemm_kernel<<<ggrid, 512, 0, stream>>>(xpad, Wt0, b0, conv);
  scan_phase1<<<sgrid, 256, 0, stream>>>(conv, carA, carB);
  scan_phase2<<<16, 256, 0, stream>>>(carA, carB, hst, h0);
  scan_phase3<0><<<sgrid, 256, 0, stream>>>(conv, hst, xpad, nullptr);

  gemm_kernel<<<ggrid, 512, 0, stream>>>(xpad, Wt1, b1, conv);
  scan_phase1<<<sgrid, 256, 0, stream>>>(conv, carA, carB);
  scan_phase2<<<16, 256, 0, stream>>>(carA, carB, hst, h1);
  scan_phase3<1><<<sgrid, 256, 0, stream>>>(conv, hst, nullptr, out_main);
}

// Round 5
// 461.925 us; speedup vs baseline: 1.2251x; 1.2251x over previous
//
#include <hip/hip_runtime.h>
#include <cstdint>

#define B_ 8
#define T_ 4096
#define TP1 4097
#define IN_ 512
#define H_ 512
#define N3H 1536
#define KD 1024
#define CHUNKS 64
#define CLEN 64   // T_/CHUNKS
#define NT 16     // KD/64 K-tiles
#define NBLK 256  // fused-scan grid (1 block/CU, co-resident)

typedef __attribute__((ext_vector_type(4))) float floatx4;
typedef __attribute__((ext_vector_type(4))) float f4;
typedef __attribute__((ext_vector_type(8))) short short8;
typedef __attribute__((ext_vector_type(4))) unsigned short us4;
typedef __attribute__((ext_vector_type(4))) _Float16 h4;

__device__ __forceinline__ unsigned short f2bf(float v){
  unsigned int u = __float_as_uint(v);
  unsigned int r = (u + 0x7fffu + ((u >> 16) & 1u)) >> 16;
  return (unsigned short)r;
}
// fast sigmoid: one v_exp_f32 + one v_rcp_f32 (no IEEE div sequence)
__device__ __forceinline__ float sigm(float x){
  return __builtin_amdgcn_rcpf(1.f + __expf(-x));
}
__device__ __forceinline__ float tanhf_(float x){ return 2.f*sigm(2.f*x) - 1.f; }

#define GLLS(src, dst) __builtin_amdgcn_global_load_lds( \
    (const __attribute__((address_space(1))) void*)(src), \
    (__attribute__((address_space(3))) void*)(dst), 16, 0, 0)

// prep: zero barrier counters + cast x->xpad bf16 (causal pad row) + transpose
// both weight tensors to k-major bf16. One launch replaces cast_pad + wt.
__global__ void prep_kernel(const float* __restrict__ x, unsigned short* __restrict__ xpad,
                            const float* __restrict__ w0, unsigned short* __restrict__ Wt0,
                            const float* __restrict__ w1, unsigned short* __restrict__ Wt1,
                            int* __restrict__ bar){
  if (blockIdx.x == 0 && threadIdx.x < 4) bar[threadIdx.x] = 0;
  int64_t i = (int64_t)blockIdx.x*256 + threadIdx.x;
  const int64_t castN = (int64_t)B_*TP1*(IN_/4);
  if (i < castN){
    int cg = (int)(i & 127);
    int64_t r = i >> 7;                                    // row (b*TP1 + t)
    int t = (int)(r % TP1);
    int b = (int)(r / TP1);
    us4 o;
    if (t == 0){ o = (us4){0,0,0,0}; }
    else {
      f4 v = *(const f4*)(x + ((int64_t)b*T_ + (t-1))*IN_ + cg*4);
      #pragma unroll
      for (int u=0;u<4;++u) o[u] = f2bf(v[u]);
    }
    *(us4*)(xpad + r*IN_ + cg*4) = o;
  } else {
    int64_t j = i - castN;                                 // over 2*N3H*512
    int layer = (j >= (int64_t)N3H*512);
    int jj = (int)(j - (int64_t)layer*N3H*512);
    const float* w = layer ? w1 : w0;
    unsigned short* wt = layer ? Wt1 : Wt0;
    int ci = jj & 511;
    int o = jj >> 9;
    const float* wp = w + (int64_t)o*KD + ci*2;
    wt[(int64_t)o*KD + ci]       = f2bf(wp[0]);
    wt[(int64_t)o*KD + 512 + ci] = f2bf(wp[1]);
  }
}

// ---------------------------------------------------------------------------
// 256x256x64 8-phase GEMM (T2 swizzle + T3/T4 counted vmcnt + T5 setprio).
// Verified R1 configuration: 111.5 us, MfmaUtil 39%, bank conflicts 0.
// C[m][n] = act(sum_k A[m][k]*W[n][k] + bias[n]) stored f16.
// 512 thr = 8 waves (2M x 4N); per-wave C = 128x64; 128 KiB LDS dbuf.
// LDS layout (shorts): A: d*16384 + row*64 + physSlot*8 ; B: +32768.
//   physSlot = logicalSlot ^ (row&7)  (16B slots; conflict-free ds_read_b128)
//   global_load_lds writes linearly; swizzle applied by pre-permuting the
//   per-lane GLOBAL source slot: srcSlot = (lane&7)^(lane>>3).
// vmcnt(4) once per tile; vmcnt(0) only at t=NT-2.
// ---------------------------------------------------------------------------
#define MFMA(a,b,c) __builtin_amdgcn_mfma_f32_16x16x32_bf16(a,b,c,0,0,0)
#define BAR() __builtin_amdgcn_s_barrier()

#define ST_A(tt, h) do { \
    const unsigned short* _s = aSrc + (h)*128*IN_ + (tt)*64; \
    unsigned short* _d = smem + ((tt)&1)*16384 + (h)*8192 + dstBase; \
    GLLS(_s, _d); GLLS(_s + 64*IN_, _d + 4096); } while(0)
#define ST_B(tt, h) do { \
    const unsigned short* _s = bSrc + (h)*128*KD + (tt)*64; \
    unsigned short* _d = smem + 32768 + ((tt)&1)*16384 + (h)*8192 + dstBase; \
    GLLS(_s, _d); GLLS(_s + 64*KD, _d + 4096); } while(0)

#define LDA(d,h,i,s) (*(const short8*)(smem + (d)*16384 + (h)*8192 + aRd + (i)*1024 + (s)))
#define LDB(d,h,i,s) (*(const short8*)(smem + (d)*16384 + (h)*8192 + bRd + (i)*1024 + (s)))

#define TILE(tc, SA1, SB1, SA0, SB0, VMN) do { \
  const int d_ = (tc) & 1; \
  /* q0: read A-half0 (m0..3) + B-half0 (n0..1); stage A1(t+1) */ \
  _Pragma("unroll") for (int i=0;i<4;++i){ aF[i][0]=LDA(d_,0,i,sw0); aF[i][1]=LDA(d_,0,i,sw1); } \
  _Pragma("unroll") for (int j=0;j<2;++j){ bF0[j][0]=LDB(d_,0,j,sw0); bF0[j][1]=LDB(d_,0,j,sw1); } \
  if (SA1) ST_A((tc)+1, 1); \
  BAR(); \
  __builtin_amdgcn_s_setprio(1); \
  _Pragma("unroll") for (int i=0;i<4;++i) _Pragma("unroll") for (int j=0;j<2;++j){ \
    acc[i][j]=MFMA(aF[i][0],bF0[j][0],acc[i][j]); acc[i][j]=MFMA(aF[i][1],bF0[j][1],acc[i][j]); } \
  __builtin_amdgcn_s_setprio(0); \
  BAR(); \
  /* q1: read B-half1 (n2..3); stage B1(t+1) */ \
  _Pragma("unroll") for (int j=0;j<2;++j){ bF1[j][0]=LDB(d_,1,j,sw0); bF1[j][1]=LDB(d_,1,j,sw1); } \
  if (SB1) ST_B((tc)+1, 1); \
  BAR(); \
  __builtin_amdgcn_s_setprio(1); \
  _Pragma("unroll") for (int i=0;i<4;++i) _Pragma("unroll") for (int j=0;j<2;++j){ \
    acc[i][2+j]=MFMA(aF[i][0],bF1[j][0],acc[i][2+j]); acc[i][2+j]=MFMA(aF[i][1],bF1[j][1],acc[i][2+j]); } \
  __builtin_amdgcn_s_setprio(0); \
  BAR(); \
  /* q2: read A-half1 (m4..7); stage A0(t+2) */ \
  _Pragma("unroll") for (int i=0;i<4;++i){ aF[i][0]=LDA(d_,1,i,sw0); aF[i][1]=LDA(d_,1,i,sw1); } \
  if (SA0) ST_A((tc)+2, 0); \
  BAR(); \
  __builtin_amdgcn_s_setprio(1); \
  _Pragma("unroll") for (int i=0;i<4;++i) _Pragma("unroll") for (int j=0;j<2;++j){ \
    acc[4+i][j]=MFMA(aF[i][0],bF0[j][0],acc[4+i][j]); acc[4+i][j]=MFMA(aF[i][1],bF0[j][1],acc[4+i][j]); } \
  __builtin_amdgcn_s_setprio(0); \
  BAR(); \
  /* q3: stage B0(t+2); MFMA m4..7 x n2..3; counted vmcnt at tile boundary */ \
  if (SB0) ST_B((tc)+2, 0); \
  BAR(); \
  __builtin_amdgcn_s_setprio(1); \
  _Pragma("unroll") for (int i=0;i<4;++i) _Pragma("unroll") for (int j=0;j<2;++j){ \
    acc[4+i][2+j]=MFMA(aF[i][0],bF1[j][0],acc[4+i][2+j]); acc[4+i][2+j]=MFMA(aF[i][1],bF1[j][1],acc[4+i][2+j]); } \
  __builtin_amdgcn_s_setprio(0); \
  if ((VMN)==4) asm volatile("s_waitcnt vmcnt(4)" ::: "memory"); \
  else if ((VMN)==0) asm volatile("s_waitcnt vmcnt(0)" ::: "memory"); \
  BAR(); \
} while(0)

__global__ __launch_bounds__(512, 2) void gemm_kernel(
    const unsigned short* __restrict__ A, const unsigned short* __restrict__ W,
    const float* __restrict__ bias, _Float16* __restrict__ C){
  __shared__ unsigned short smem[65536];   // 128 KiB: A [0,32768), B [32768,65536)
  const int tid  = threadIdx.x;
  const int lane = tid & 63;
  const int wave = tid >> 6;
  const int l16  = lane & 15;
  const int quad = lane >> 4;
  const int wm = wave >> 2;      // 0..1 (M)
  const int wn = wave & 3;       // 0..3 (N)
  const int lrow = lane >> 3;    // 0..7
  const int lcol = lane & 7;     // 0..7

  // XCD-bijective chunked swizzle (768 = 8 xcd * 96); m-major / n-inner per chunk
  const int bid = blockIdx.x;
  const int wg = (bid & 7) * 96 + (bid >> 3);
  const int mt = wg / 6;
  const int nt = wg % 6;
  const int m0 = mt * 256;
  const int n0 = nt * 256;
  const int bb = m0 / T_;               // tile fully inside one batch (256 | 4096)
  const int act = n0 >> 9;              // 0=z(tanh), 1=f(sigm), 2=o(sigm)

  // staging: lane writes LDS linearly (row = wave*8+lrow, slot = lcol);
  // source slot pre-swizzled so LDS physSlot p holds logical p^(row&7)
  const unsigned short* aSrc = A + (int64_t)(m0 + bb + wave*8 + lrow)*IN_ + (lcol ^ lrow)*8;
  const unsigned short* bSrc = W + (int64_t)(n0 + wave*8 + lrow)*KD + (lcol ^ lrow)*8;
  const int dstBase = (wave*8 + lrow)*64 + lcol*8;   // shorts; == lane*16B per wave

  // ds_read bases (shorts); fragment row&7 == l16&7
  const int sw0 = ( quad      ^ (l16 & 7)) * 8;      // k-substep s=0
  const int sw1 = ((4 ^ quad) ^ (l16 & 7)) * 8;      // k-substep s=1
  const int aRd = (wm*64 + l16)*64;
  const int bRd = 32768 + (wn*32 + l16)*64;

  floatx4 acc[8][4];
  #pragma unroll
  for (int i=0;i<8;i++)
    #pragma unroll
    for (int j=0;j<4;j++) acc[i][j] = (floatx4){0.f,0.f,0.f,0.f};
  short8 aF[4][2], bF0[2][2], bF1[2][2];

  // prologue: tile0 {A0,B0,A1,B1} + tile1 {A0,B0}; allow last 2 half-tiles in flight
  ST_A(0,0); ST_B(0,0); ST_A(0,1); ST_B(0,1); ST_A(1,0); ST_B(1,0);
  asm volatile("s_waitcnt vmcnt(4)" ::: "memory");
  BAR();

  #pragma unroll 2
  for (int t = 0; t < NT-2; ++t){
    TILE(t, 1, 1, 1, 1, 4);
  }
  TILE(NT-2, 1, 1, 0, 0, 0);
  TILE(NT-1, 0, 0, 0, 0, -1);

  // epilogue: bias + activation, f16 store (C/D map: row=quad*4+r, col=l16)
  float bv[4];
  #pragma unroll
  for (int n=0;n<4;++n){
    const int cb = ((n&2)?128:0) + wn*32 + (n&1)*16;
    bv[n] = bias[n0 + cb + l16];
  }
  #pragma unroll
  for (int m=0;m<8;++m){
    const int rb = ((m&4)?128:0) + wm*64 + (m&3)*16;
    const int row = m0 + rb + quad*4;
    #pragma unroll
    for (int n=0;n<4;++n){
      const int cb = ((n&2)?128:0) + wn*32 + (n&1)*16;
      const int col = n0 + cb + l16;
      _Float16* cp = C + (int64_t)row*N3H + col;
      #pragma unroll
      for (int r=0;r<4;++r){
        float v = acc[m][n][r] + bv[n];
        v = (act == 0) ? tanhf_(v) : sigm(v);
        cp[(int64_t)r*N3H] = (_Float16)v;
      }
    }
  }
}

// device-scope grid barrier: producer threadfence -> arrive (atomicAdd) ->
// spin on atomic read -> acquire fence. Grid must be exactly NBLK co-resident
// blocks (1/CU, tiny resources -> guaranteed).
__device__ __forceinline__ void gridbar(int* bar, int id){
  __syncthreads();
  if (threadIdx.x == 0){
    __threadfence();
    atomicAdd(&bar[id], 1);
    while (atomicAdd(&bar[id], 0) < NBLK) __builtin_amdgcn_s_sleep(8);
    __threadfence();
  }
  __syncthreads();
}

// fused scan: p1 (chunk affine) -> gridbar -> p2 (chunk scan, blocks 0..15)
// -> gridbar -> p3 (replay + o*h). Bodies/indexing identical to verified R1.
template<int LAYER>
__global__ void scan_fused(const _Float16* __restrict__ conv,
                           float* __restrict__ carA, float* __restrict__ carB,
                           float* __restrict__ hstart, float* __restrict__ hT,
                           unsigned short* __restrict__ xpad, float* __restrict__ outf,
                           int* __restrict__ bar){
  const int q = blockIdx.x*256 + threadIdx.x;   // 65536
  const int chg = q & 127;
  const int bq = (q >> 7) & 7;
  const int c  = q >> 10;
  const int ch = chg*4;
  const _Float16* pbase = conv + ((int64_t)bq*T_ + c*CLEN)*N3H + ch;

  // ---- phase 1: per-chunk affine composition ----
  {
    f4 Aa = {1.f,1.f,1.f,1.f}, Bb = {0.f,0.f,0.f,0.f};
    const _Float16* p = pbase;
    for (int g=0; g<CLEN/8; ++g){
      h4 zb[8], fb[8];
      #pragma unroll
      for (int u=0;u<8;++u){
        zb[u] = *(const h4*)(p + (int64_t)u*N3H);
        fb[u] = *(const h4*)(p + (int64_t)u*N3H + 512);
      }
      #pragma unroll
      for (int u=0;u<8;++u){
        #pragma unroll
        for (int v=0;v<4;++v){
          float fv = (float)fb[u][v];
          float zv = (float)zb[u][v];
          Aa[v] *= fv;
          Bb[v] = fv*Bb[v] + (1.f-fv)*zv;
        }
      }
      p += (int64_t)8*N3H;
    }
    *(f4*)(carA + (int64_t)q*4) = Aa;
    *(f4*)(carB + (int64_t)q*4) = Bb;
  }
  gridbar(bar, 2*LAYER);

  // ---- phase 2: scan over chunks (blocks 0..15 = 4096 channels) ----
  if (blockIdx.x < 16){
    float h = 0.f;
    for (int cc=0;cc<CHUNKS;++cc){
      int64_t idx = (int64_t)cc*4096 + q;
      hstart[idx] = h;
      h = carA[idx]*h + carB[idx];
    }
    hT[q] = h;
  }
  gridbar(bar, 2*LAYER+1);

  // ---- phase 3: replay chunk with true h-start, apply o*h ----
  {
    f4 h;
    #pragma unroll
    for (int v=0;v<4;++v) h[v] = hstart[(int64_t)c*4096 + bq*512 + ch + v];
    const _Float16* p = pbase;
    int t = c*CLEN;
    for (int g=0; g<CLEN/8; ++g){
      h4 zb[8], fb[8], ob[8];
      #pragma unroll
      for (int u=0;u<8;++u){
        zb[u] = *(const h4*)(p + (int64_t)u*N3H);
        fb[u] = *(const h4*)(p + (int64_t)u*N3H + 512);
        ob[u] = *(const h4*)(p + (int64_t)u*N3H + 1024);
      }
      #pragma unroll
      for (int u=0;u<8;++u){
        if (LAYER == 0){
          us4 ov4;
          #pragma unroll
          for (int v=0;v<4;++v){
            float fv = (float)fb[u][v];
            h[v] = fv*h[v] + (1.f-fv)*(float)zb[u][v];
            ov4[v] = f2bf((float)ob[u][v]*h[v]);
          }
          *(us4*)(xpad + ((int64_t)bq*TP1 + t+u + 1)*IN_ + ch) = ov4;
        } else {
          f4 of4;
          #pragma unroll
          for (int v=0;v<4;++v){
            float fv = (float)fb[u][v];
            h[v] = fv*h[v] + (1.f-fv)*(float)zb[u][v];
            of4[v] = (float)ob[u][v]*h[v];
          }
          *(f4*)(outf + ((int64_t)bq*T_ + t+u)*H_ + ch) = of4;
        }
      }
      t += 8; p += (int64_t)8*N3H;
    }
  }
}

extern "C" void kernel_launch(void* const* d_in, const int* in_sizes, int n_in,
                              void* d_out, int out_size, void* d_ws, size_t ws_size,
                              hipStream_t stream){
  const float* x  = (const float*)d_in[0];
  const float* w0 = (const float*)d_in[1];
  const float* b0 = (const float*)d_in[2];
  const float* w1 = (const float*)d_in[3];
  const float* b1 = (const float*)d_in[4];
  float* out = (float*)d_out;

  char* ws = (char*)d_ws;
  size_t off = 0;
  auto alloc = [&](size_t bytes)->char*{
    char* p = ws + off; off = (off + bytes + 255) & ~(size_t)255; return p; };
  unsigned short* xpad = (unsigned short*)alloc((size_t)B_*TP1*IN_*2);
  unsigned short* Wt0  = (unsigned short*)alloc((size_t)N3H*KD*2);
  unsigned short* Wt1  = (unsigned short*)alloc((size_t)N3H*KD*2);
  _Float16* conv = (_Float16*)alloc((size_t)B_*T_*N3H*2);
  float* carA = (float*)alloc((size_t)CHUNKS*4096*4);
  float* carB = (float*)alloc((size_t)CHUNKS*4096*4);
  float* hst  = (float*)alloc((size_t)CHUNKS*4096*4);
  int*   bar  = (int*)alloc(4*sizeof(int));
  if (off > ws_size) return;  // workspace too small -> fail loudly in validation

  float* out_main = out;
  float* h0 = out + (int64_t)B_*T_*H_;
  float* h1 = h0 + B_*H_;

  // prep: bar zeroing + cast_pad + both weight transposes in one launch
  const int64_t castN = (int64_t)B_*TP1*(IN_/4);
  const int64_t prepN = castN + (int64_t)2*N3H*512;
  prep_kernel<<<(int)((prepN + 255)/256), 256, 0, stream>>>(x, xpad, w0, Wt0, w1, Wt1, bar);

  const int ggrid = ((B_*T_)/256) * (N3H/256);   // 128*6 = 768
  gemm_kernel<<<ggrid, 512, 0, stream>>>(xpad, Wt0, b0, conv);
  scan_fused<0><<<NBLK, 256, 0, stream>>>(conv, carA, carB, hst, h0, xpad, nullptr, bar);

  gemm_kernel<<<ggrid, 512, 0, stream>>>(xpad, Wt1, b1, conv);
  scan_fused<1><<<NBLK, 256, 0, stream>>>(conv, carA, carB, hst, h1, nullptr, out_main, bar);
}

// Round 6
// 435.099 us; speedup vs baseline: 1.3006x; 1.0617x over previous
//
#include <hip/hip_runtime.h>
#include <cstdint>

#define B_ 8
#define T_ 4096
#define TP1 4097
#define IN_ 512
#define H_ 512
#define N3H 1536
#define KD 1024
#define CHUNKS 64
#define CLEN 64   // T_/CHUNKS
#define NT 16     // KD/64 K-tiles

typedef __attribute__((ext_vector_type(4))) float floatx4;
typedef __attribute__((ext_vector_type(4))) float f4;
typedef __attribute__((ext_vector_type(8))) short short8;
typedef __attribute__((ext_vector_type(4))) unsigned short us4;
typedef __attribute__((ext_vector_type(4))) _Float16 h4;

__device__ __forceinline__ unsigned short f2bf(float v){
  unsigned int u = __float_as_uint(v);
  unsigned int r = (u + 0x7fffu + ((u >> 16) & 1u)) >> 16;
  return (unsigned short)r;
}
// fast sigmoid: one v_exp_f32 + one v_rcp_f32 (no IEEE div sequence)
__device__ __forceinline__ float sigm(float x){
  return __builtin_amdgcn_rcpf(1.f + __expf(-x));
}
__device__ __forceinline__ float tanhf_(float x){ return 2.f*sigm(2.f*x) - 1.f; }

#define GLLS(src, dst) __builtin_amdgcn_global_load_lds( \
    (const __attribute__((address_space(1))) void*)(src), \
    (__attribute__((address_space(3))) void*)(dst), 16, 0, 0)

// x f32 [B,T,IN] -> xpad bf16 [B, T+1, IN] with zero row at t'=0 (causal pad)
__global__ void cast_pad_kernel(const float* __restrict__ x, unsigned short* __restrict__ xpad){
  int64_t i = (int64_t)blockIdx.x*256 + threadIdx.x;       // over B*TP1*(IN/4)
  const int64_t total = (int64_t)B_*TP1*(IN_/4);
  if (i >= total) return;
  int cg = (int)(i & 127);
  int64_t r = i >> 7;                                      // row (b*TP1 + t)
  int t = (int)(r % TP1);
  int b = (int)(r / TP1);
  us4 o;
  if (t == 0){ o = (us4){0,0,0,0}; }
  else {
    f4 v = *(const f4*)(x + ((int64_t)b*T_ + (t-1))*IN_ + cg*4);
    #pragma unroll
    for (int u=0;u<4;++u) o[u] = f2bf(v[u]);
  }
  *(us4*)(xpad + r*IN_ + cg*4) = o;
}

// w f32 [3H, IN, K=2] -> wt bf16 [3H, 1024], k-major halves; blockIdx.y picks layer
__global__ void wt_kernel(const float* __restrict__ wA, unsigned short* __restrict__ wtA,
                          const float* __restrict__ wB, unsigned short* __restrict__ wtB){
  int i = blockIdx.x*256 + threadIdx.x;                    // over N3H*512
  if (i >= N3H*512) return;
  const float* w = blockIdx.y ? wB : wA;
  unsigned short* wt = blockIdx.y ? wtB : wtA;
  int ci = i & 511;
  int o = i >> 9;
  const float* wp = w + (int64_t)o*KD + ci*2;
  wt[(int64_t)o*KD + ci]       = f2bf(wp[0]);
  wt[(int64_t)o*KD + 512 + ci] = f2bf(wp[1]);
}

// ---------------------------------------------------------------------------
// 256x256x64 8-phase GEMM (T2 swizzle + T3/T4 counted vmcnt + T5 setprio).
// Verified R1 configuration: 111.5 us, MfmaUtil 39%, bank conflicts 0.
// C[m][n] = act(sum_k A[m][k]*W[n][k] + bias[n]) stored f16.
// 512 thr = 8 waves (2M x 4N); per-wave C = 128x64; 128 KiB LDS dbuf.
// LDS layout (shorts): A: d*16384 + row*64 + physSlot*8 ; B: +32768.
//   physSlot = logicalSlot ^ (row&7)  (16B slots; conflict-free ds_read_b128)
//   global_load_lds writes linearly; swizzle applied by pre-permuting the
//   per-lane GLOBAL source slot: srcSlot = (lane&7)^(lane>>3).
// vmcnt(4) once per tile; vmcnt(0) only at t=NT-2.
// ---------------------------------------------------------------------------
#define MFMA(a,b,c) __builtin_amdgcn_mfma_f32_16x16x32_bf16(a,b,c,0,0,0)
#define BAR() __builtin_amdgcn_s_barrier()

#define ST_A(tt, h) do { \
    const unsigned short* _s = aSrc + (h)*128*IN_ + (tt)*64; \
    unsigned short* _d = smem + ((tt)&1)*16384 + (h)*8192 + dstBase; \
    GLLS(_s, _d); GLLS(_s + 64*IN_, _d + 4096); } while(0)
#define ST_B(tt, h) do { \
    const unsigned short* _s = bSrc + (h)*128*KD + (tt)*64; \
    unsigned short* _d = smem + 32768 + ((tt)&1)*16384 + (h)*8192 + dstBase; \
    GLLS(_s, _d); GLLS(_s + 64*KD, _d + 4096); } while(0)

#define LDA(d,h,i,s) (*(const short8*)(smem + (d)*16384 + (h)*8192 + aRd + (i)*1024 + (s)))
#define LDB(d,h,i,s) (*(const short8*)(smem + (d)*16384 + (h)*8192 + bRd + (i)*1024 + (s)))

#define TILE(tc, SA1, SB1, SA0, SB0, VMN) do { \
  const int d_ = (tc) & 1; \
  /* q0: read A-half0 (m0..3) + B-half0 (n0..1); stage A1(t+1) */ \
  _Pragma("unroll") for (int i=0;i<4;++i){ aF[i][0]=LDA(d_,0,i,sw0); aF[i][1]=LDA(d_,0,i,sw1); } \
  _Pragma("unroll") for (int j=0;j<2;++j){ bF0[j][0]=LDB(d_,0,j,sw0); bF0[j][1]=LDB(d_,0,j,sw1); } \
  if (SA1) ST_A((tc)+1, 1); \
  BAR(); \
  __builtin_amdgcn_s_setprio(1); \
  _Pragma("unroll") for (int i=0;i<4;++i) _Pragma("unroll") for (int j=0;j<2;++j){ \
    acc[i][j]=MFMA(aF[i][0],bF0[j][0],acc[i][j]); acc[i][j]=MFMA(aF[i][1],bF0[j][1],acc[i][j]); } \
  __builtin_amdgcn_s_setprio(0); \
  BAR(); \
  /* q1: read B-half1 (n2..3); stage B1(t+1) */ \
  _Pragma("unroll") for (int j=0;j<2;++j){ bF1[j][0]=LDB(d_,1,j,sw0); bF1[j][1]=LDB(d_,1,j,sw1); } \
  if (SB1) ST_B((tc)+1, 1); \
  BAR(); \
  __builtin_amdgcn_s_setprio(1); \
  _Pragma("unroll") for (int i=0;i<4;++i) _Pragma("unroll") for (int j=0;j<2;++j){ \
    acc[i][2+j]=MFMA(aF[i][0],bF1[j][0],acc[i][2+j]); acc[i][2+j]=MFMA(aF[i][1],bF1[j][1],acc[i][2+j]); } \
  __builtin_amdgcn_s_setprio(0); \
  BAR(); \
  /* q2: read A-half1 (m4..7); stage A0(t+2) */ \
  _Pragma("unroll") for (int i=0;i<4;++i){ aF[i][0]=LDA(d_,1,i,sw0); aF[i][1]=LDA(d_,1,i,sw1); } \
  if (SA0) ST_A((tc)+2, 0); \
  BAR(); \
  __builtin_amdgcn_s_setprio(1); \
  _Pragma("unroll") for (int i=0;i<4;++i) _Pragma("unroll") for (int j=0;j<2;++j){ \
    acc[4+i][j]=MFMA(aF[i][0],bF0[j][0],acc[4+i][j]); acc[4+i][j]=MFMA(aF[i][1],bF0[j][1],acc[4+i][j]); } \
  __builtin_amdgcn_s_setprio(0); \
  BAR(); \
  /* q3: stage B0(t+2); MFMA m4..7 x n2..3; counted vmcnt at tile boundary */ \
  if (SB0) ST_B((tc)+2, 0); \
  BAR(); \
  __builtin_amdgcn_s_setprio(1); \
  _Pragma("unroll") for (int i=0;i<4;++i) _Pragma("unroll") for (int j=0;j<2;++j){ \
    acc[4+i][2+j]=MFMA(aF[i][0],bF1[j][0],acc[4+i][2+j]); acc[4+i][2+j]=MFMA(aF[i][1],bF1[j][1],acc[4+i][2+j]); } \
  __builtin_amdgcn_s_setprio(0); \
  if ((VMN)==4) asm volatile("s_waitcnt vmcnt(4)" ::: "memory"); \
  else if ((VMN)==0) asm volatile("s_waitcnt vmcnt(0)" ::: "memory"); \
  BAR(); \
} while(0)

__global__ __launch_bounds__(512, 2) void gemm_kernel(
    const unsigned short* __restrict__ A, const unsigned short* __restrict__ W,
    const float* __restrict__ bias, _Float16* __restrict__ C){
  __shared__ unsigned short smem[65536];   // 128 KiB: A [0,32768), B [32768,65536)
  const int tid  = threadIdx.x;
  const int lane = tid & 63;
  const int wave = tid >> 6;
  const int l16  = lane & 15;
  const int quad = lane >> 4;
  const int wm = wave >> 2;      // 0..1 (M)
  const int wn = wave & 3;       // 0..3 (N)
  const int lrow = lane >> 3;    // 0..7
  const int lcol = lane & 7;     // 0..7

  // XCD-bijective chunked swizzle (768 = 8 xcd * 96); m-major / n-inner per chunk
  const int bid = blockIdx.x;
  const int wg = (bid & 7) * 96 + (bid >> 3);
  const int mt = wg / 6;
  const int nt = wg % 6;
  const int m0 = mt * 256;
  const int n0 = nt * 256;
  const int bb = m0 / T_;               // tile fully inside one batch (256 | 4096)
  const int act = n0 >> 9;              // 0=z(tanh), 1=f(sigm), 2=o(sigm)

  // staging: lane writes LDS linearly (row = wave*8+lrow, slot = lcol);
  // source slot pre-swizzled so LDS physSlot p holds logical p^(row&7)
  const unsigned short* aSrc = A + (int64_t)(m0 + bb + wave*8 + lrow)*IN_ + (lcol ^ lrow)*8;
  const unsigned short* bSrc = W + (int64_t)(n0 + wave*8 + lrow)*KD + (lcol ^ lrow)*8;
  const int dstBase = (wave*8 + lrow)*64 + lcol*8;   // shorts; == lane*16B per wave

  // ds_read bases (shorts); fragment row&7 == l16&7
  const int sw0 = ( quad      ^ (l16 & 7)) * 8;      // k-substep s=0
  const int sw1 = ((4 ^ quad) ^ (l16 & 7)) * 8;      // k-substep s=1
  const int aRd = (wm*64 + l16)*64;
  const int bRd = 32768 + (wn*32 + l16)*64;

  floatx4 acc[8][4];
  #pragma unroll
  for (int i=0;i<8;i++)
    #pragma unroll
    for (int j=0;j<4;j++) acc[i][j] = (floatx4){0.f,0.f,0.f,0.f};
  short8 aF[4][2], bF0[2][2], bF1[2][2];

  // prologue: tile0 {A0,B0,A1,B1} + tile1 {A0,B0}; allow last 2 half-tiles in flight
  ST_A(0,0); ST_B(0,0); ST_A(0,1); ST_B(0,1); ST_A(1,0); ST_B(1,0);
  asm volatile("s_waitcnt vmcnt(4)" ::: "memory");
  BAR();

  #pragma unroll 2
  for (int t = 0; t < NT-2; ++t){
    TILE(t, 1, 1, 1, 1, 4);
  }
  TILE(NT-2, 1, 1, 0, 0, 0);
  TILE(NT-1, 0, 0, 0, 0, -1);

  // epilogue: bias + activation, f16 store (C/D map: row=quad*4+r, col=l16)
  float bv[4];
  #pragma unroll
  for (int n=0;n<4;++n){
    const int cb = ((n&2)?128:0) + wn*32 + (n&1)*16;
    bv[n] = bias[n0 + cb + l16];
  }
  #pragma unroll
  for (int m=0;m<8;++m){
    const int rb = ((m&4)?128:0) + wm*64 + (m&3)*16;
    const int row = m0 + rb + quad*4;
    #pragma unroll
    for (int n=0;n<4;++n){
      const int cb = ((n&2)?128:0) + wn*32 + (n&1)*16;
      const int col = n0 + cb + l16;
      _Float16* cp = C + (int64_t)row*N3H + col;
      #pragma unroll
      for (int r=0;r<4;++r){
        float v = acc[m][n][r] + bv[n];
        v = (act == 0) ? tanhf_(v) : sigm(v);
        cp[(int64_t)r*N3H] = (_Float16)v;
      }
    }
  }
}

// phase 1: per-chunk affine composition (Aa, Bb): h_out = Aa*h_in + Bb
__global__ void scan_phase1(const _Float16* __restrict__ conv,
                            float* __restrict__ carA, float* __restrict__ carB){
  int q = blockIdx.x*256 + threadIdx.x;     // CHUNKS*8*128 = 65536
  int chg = q & 127;
  int bq = (q >> 7) & 7;
  int c  = q >> 10;
  int ch = chg*4;
  f4 Aa = {1.f,1.f,1.f,1.f}, Bb = {0.f,0.f,0.f,0.f};
  const _Float16* p = conv + ((int64_t)bq*T_ + c*CLEN)*N3H + ch;
  for (int g=0; g<CLEN/8; ++g){
    h4 zb[8], fb[8];
    #pragma unroll
    for (int u=0;u<8;++u){
      zb[u] = *(const h4*)(p + (int64_t)u*N3H);
      fb[u] = *(const h4*)(p + (int64_t)u*N3H + 512);
    }
    #pragma unroll
    for (int u=0;u<8;++u){
      #pragma unroll
      for (int v=0;v<4;++v){
        float fv = (float)fb[u][v];
        float zv = (float)zb[u][v];
        Aa[v] *= fv;
        Bb[v] = fv*Bb[v] + (1.f-fv)*zv;
      }
    }
    p += (int64_t)8*N3H;
  }
  *(f4*)(carA + (int64_t)q*4) = Aa;
  *(f4*)(carB + (int64_t)q*4) = Bb;
}

// phase 2: scan over chunks; emit h at chunk starts + final hT. 1 channel/thread.
// Batch-of-8 hoisted loads keep 16 independent loads in flight ahead of the
// serial fma chain (addresses data-independent; __restrict rules out aliasing
// with the hstart stores). 64 blocks x 64 threads spreads the 4096 channels
// over 64 CUs instead of 16.
__global__ void scan_phase2(const float* __restrict__ carA, const float* __restrict__ carB,
                            float* __restrict__ hstart, float* __restrict__ hT){
  int q = blockIdx.x*64 + threadIdx.x;      // 4096 channels (b*512+ch)
  float h = 0.f;
  for (int c0=0;c0<CHUNKS;c0+=8){
    float a[8], b[8];
    #pragma unroll
    for (int u=0;u<8;++u){
      a[u] = carA[(int64_t)(c0+u)*4096 + q];
      b[u] = carB[(int64_t)(c0+u)*4096 + q];
    }
    #pragma unroll
    for (int u=0;u<8;++u){
      hstart[(int64_t)(c0+u)*4096 + q] = h;
      h = a[u]*h + b[u];
    }
  }
  hT[q] = h;
}

// phase 3: replay chunk with true h-start, apply o*h, write output
template<int LAYER>
__global__ void scan_phase3(const _Float16* __restrict__ conv,
                            const float* __restrict__ hstart, unsigned short* __restrict__ xpad,
                            float* __restrict__ outf){
  int q = blockIdx.x*256 + threadIdx.x;     // 65536
  int chg = q & 127;
  int bq = (q >> 7) & 7;
  int c  = q >> 10;
  int ch = chg*4;
  f4 h;
  #pragma unroll
  for (int v=0;v<4;++v) h[v] = hstart[(int64_t)c*4096 + bq*512 + ch + v];
  const _Float16* p = conv + ((int64_t)bq*T_ + c*CLEN)*N3H + ch;
  int t = c*CLEN;
  for (int g=0; g<CLEN/8; ++g){
    h4 zb[8], fb[8], ob[8];
    #pragma unroll
    for (int u=0;u<8;++u){
      zb[u] = *(const h4*)(p + (int64_t)u*N3H);
      fb[u] = *(const h4*)(p + (int64_t)u*N3H + 512);
      ob[u] = *(const h4*)(p + (int64_t)u*N3H + 1024);
    }
    #pragma unroll
    for (int u=0;u<8;++u){
      if (LAYER == 0){
        us4 ov4;
        #pragma unroll
        for (int v=0;v<4;++v){
          float fv = (float)fb[u][v];
          h[v] = fv*h[v] + (1.f-fv)*(float)zb[u][v];
          ov4[v] = f2bf((float)ob[u][v]*h[v]);
        }
        *(us4*)(xpad + ((int64_t)bq*TP1 + t+u + 1)*IN_ + ch) = ov4;
      } else {
        f4 of4;
        #pragma unroll
        for (int v=0;v<4;++v){
          float fv = (float)fb[u][v];
          h[v] = fv*h[v] + (1.f-fv)*(float)zb[u][v];
          of4[v] = (float)ob[u][v]*h[v];
        }
        *(f4*)(outf + ((int64_t)bq*T_ + t+u)*H_ + ch) = of4;
      }
    }
    t += 8; p += (int64_t)8*N3H;
  }
}

extern "C" void kernel_launch(void* const* d_in, const int* in_sizes, int n_in,
                              void* d_out, int out_size, void* d_ws, size_t ws_size,
                              hipStream_t stream){
  const float* x  = (const float*)d_in[0];
  const float* w0 = (const float*)d_in[1];
  const float* b0 = (const float*)d_in[2];
  const float* w1 = (const float*)d_in[3];
  const float* b1 = (const float*)d_in[4];
  float* out = (float*)d_out;

  char* ws = (char*)d_ws;
  size_t off = 0;
  auto alloc = [&](size_t bytes)->char*{
    char* p = ws + off; off = (off + bytes + 255) & ~(size_t)255; return p; };
  unsigned short* xpad = (unsigned short*)alloc((size_t)B_*TP1*IN_*2);
  unsigned short* Wt0  = (unsigned short*)alloc((size_t)N3H*KD*2);
  unsigned short* Wt1  = (unsigned short*)alloc((size_t)N3H*KD*2);
  _Float16* conv = (_Float16*)alloc((size_t)B_*T_*N3H*2);
  float* carA = (float*)alloc((size_t)CHUNKS*4096*4);
  float* carB = (float*)alloc((size_t)CHUNKS*4096*4);
  float* hst  = (float*)alloc((size_t)CHUNKS*4096*4);
  if (off > ws_size) return;  // workspace too small -> fail loudly in validation

  float* out_main = out;
  float* h0 = out + (int64_t)B_*T_*H_;
  float* h1 = h0 + B_*H_;

  const int64_t padN = (int64_t)B_*TP1*(IN_/4);
  cast_pad_kernel<<<(int)((padN + 255)/256), 256, 0, stream>>>(x, xpad);
  dim3 wgrid((N3H*512 + 255)/256, 2);
  wt_kernel<<<wgrid, 256, 0, stream>>>(w0, Wt0, w1, Wt1);

  const int ggrid = ((B_*T_)/256) * (N3H/256);   // 128*6 = 768
  const int sgrid = (CHUNKS*8*128) / 256;        // 256
  gemm_kernel<<<ggrid, 512, 0, stream>>>(xpad, Wt0, b0, conv);
  scan_phase1<<<sgrid, 256, 0, stream>>>(conv, carA, carB);
  scan_phase2<<<64, 64, 0, stream>>>(carA, carB, hst, h0);
  scan_phase3<0><<<sgrid, 256, 0, stream>>>(conv, hst, xpad, nullptr);

  gemm_kernel<<<ggrid, 512, 0, stream>>>(xpad, Wt1, b1, conv);
  scan_phase1<<<sgrid, 256, 0, stream>>>(conv, carA, carB);
  scan_phase2<<<64, 64, 0, stream>>>(carA, carB, hst, h1);
  scan_phase3<1><<<sgrid, 256, 0, stream>>>(conv, hst, nullptr, out_main);
}

// Round 7
// 403.270 us; speedup vs baseline: 1.4033x; 1.0789x over previous
//
#include <hip/hip_runtime.h>
#include <cstdint>

#define B_ 8
#define T_ 4096
#define TP1 4097
#define IN_ 512
#define H_ 512
#define N3H 1536
#define KD 1024
#define CHUNKS 64
#define CLEN 64   // T_/CHUNKS
#define NT 16     // KD/64 K-tiles

typedef __attribute__((ext_vector_type(4))) float floatx4;
typedef __attribute__((ext_vector_type(4))) float f4;
typedef __attribute__((ext_vector_type(8))) short short8;
typedef __attribute__((ext_vector_type(4))) unsigned short us4;
typedef __attribute__((ext_vector_type(4))) _Float16 h4;

__device__ __forceinline__ unsigned short f2bf(float v){
  unsigned int u = __float_as_uint(v);
  unsigned int r = (u + 0x7fffu + ((u >> 16) & 1u)) >> 16;
  return (unsigned short)r;
}
// fast sigmoid: one v_exp_f32 + one v_rcp_f32 (no IEEE div sequence)
__device__ __forceinline__ float sigm(float x){
  return __builtin_amdgcn_rcpf(1.f + __expf(-x));
}
__device__ __forceinline__ float tanhf_(float x){ return 2.f*sigm(2.f*x) - 1.f; }

#define GLLS(src, dst) __builtin_amdgcn_global_load_lds( \
    (const __attribute__((address_space(1))) void*)(src), \
    (__attribute__((address_space(3))) void*)(dst), 16, 0, 0)

// prep: cast x->xpad bf16 (causal pad row) + transpose both weight tensors to
// k-major bf16. One launch replaces cast_pad + wt (merge proven harmless R5).
__global__ void prep_kernel(const float* __restrict__ x, unsigned short* __restrict__ xpad,
                            const float* __restrict__ w0, unsigned short* __restrict__ Wt0,
                            const float* __restrict__ w1, unsigned short* __restrict__ Wt1){
  int64_t i = (int64_t)blockIdx.x*256 + threadIdx.x;
  const int64_t castN = (int64_t)B_*TP1*(IN_/4);           // 4,195,328 (256-divisible)
  if (i < castN){
    int cg = (int)(i & 127);
    int64_t r = i >> 7;                                    // row (b*TP1 + t)
    int t = (int)(r % TP1);
    int b = (int)(r / TP1);
    us4 o;
    if (t == 0){ o = (us4){0,0,0,0}; }
    else {
      f4 v = *(const f4*)(x + ((int64_t)b*T_ + (t-1))*IN_ + cg*4);
      #pragma unroll
      for (int u=0;u<4;++u) o[u] = f2bf(v[u]);
    }
    *(us4*)(xpad + r*IN_ + cg*4) = o;
  } else {
    int64_t j = i - castN;                                 // over 2*N3H*512
    int layer = (j >= (int64_t)N3H*512);
    int jj = (int)(j - (int64_t)layer*N3H*512);
    const float* w = layer ? w1 : w0;
    unsigned short* wt = layer ? Wt1 : Wt0;
    int ci = jj & 511;
    int o = jj >> 9;
    const float* wp = w + (int64_t)o*KD + ci*2;
    wt[(int64_t)o*KD + ci]       = f2bf(wp[0]);
    wt[(int64_t)o*KD + 512 + ci] = f2bf(wp[1]);
  }
}

// ---------------------------------------------------------------------------
// 256x256x64 8-phase GEMM (T2 swizzle + T3/T4 counted vmcnt + T5 setprio).
// Verified R1 configuration: 111.5 us, MfmaUtil 39%, bank conflicts 0.
// C[m][n] = act(sum_k A[m][k]*W[n][k] + bias[n]) stored f16.
// 512 thr = 8 waves (2M x 4N); per-wave C = 128x64; 128 KiB LDS dbuf.
// LDS layout (shorts): A: d*16384 + row*64 + physSlot*8 ; B: +32768.
//   physSlot = logicalSlot ^ (row&7)  (16B slots; conflict-free ds_read_b128)
//   global_load_lds writes linearly; swizzle applied by pre-permuting the
//   per-lane GLOBAL source slot: srcSlot = (lane&7)^(lane>>3).
// vmcnt(4) once per tile; vmcnt(0) only at t=NT-2.
// ---------------------------------------------------------------------------
#define MFMA(a,b,c) __builtin_amdgcn_mfma_f32_16x16x32_bf16(a,b,c,0,0,0)
#define BAR() __builtin_amdgcn_s_barrier()

#define ST_A(tt, h) do { \
    const unsigned short* _s = aSrc + (h)*128*IN_ + (tt)*64; \
    unsigned short* _d = smem + ((tt)&1)*16384 + (h)*8192 + dstBase; \
    GLLS(_s, _d); GLLS(_s + 64*IN_, _d + 4096); } while(0)
#define ST_B(tt, h) do { \
    const unsigned short* _s = bSrc + (h)*128*KD + (tt)*64; \
    unsigned short* _d = smem + 32768 + ((tt)&1)*16384 + (h)*8192 + dstBase; \
    GLLS(_s, _d); GLLS(_s + 64*KD, _d + 4096); } while(0)

#define LDA(d,h,i,s) (*(const short8*)(smem + (d)*16384 + (h)*8192 + aRd + (i)*1024 + (s)))
#define LDB(d,h,i,s) (*(const short8*)(smem + (d)*16384 + (h)*8192 + bRd + (i)*1024 + (s)))

#define TILE(tc, SA1, SB1, SA0, SB0, VMN) do { \
  const int d_ = (tc) & 1; \
  /* q0: read A-half0 (m0..3) + B-half0 (n0..1); stage A1(t+1) */ \
  _Pragma("unroll") for (int i=0;i<4;++i){ aF[i][0]=LDA(d_,0,i,sw0); aF[i][1]=LDA(d_,0,i,sw1); } \
  _Pragma("unroll") for (int j=0;j<2;++j){ bF0[j][0]=LDB(d_,0,j,sw0); bF0[j][1]=LDB(d_,0,j,sw1); } \
  if (SA1) ST_A((tc)+1, 1); \
  BAR(); \
  __builtin_amdgcn_s_setprio(1); \
  _Pragma("unroll") for (int i=0;i<4;++i) _Pragma("unroll") for (int j=0;j<2;++j){ \
    acc[i][j]=MFMA(aF[i][0],bF0[j][0],acc[i][j]); acc[i][j]=MFMA(aF[i][1],bF0[j][1],acc[i][j]); } \
  __builtin_amdgcn_s_setprio(0); \
  BAR(); \
  /* q1: read B-half1 (n2..3); stage B1(t+1) */ \
  _Pragma("unroll") for (int j=0;j<2;++j){ bF1[j][0]=LDB(d_,1,j,sw0); bF1[j][1]=LDB(d_,1,j,sw1); } \
  if (SB1) ST_B((tc)+1, 1); \
  BAR(); \
  __builtin_amdgcn_s_setprio(1); \
  _Pragma("unroll") for (int i=0;i<4;++i) _Pragma("unroll") for (int j=0;j<2;++j){ \
    acc[i][2+j]=MFMA(aF[i][0],bF1[j][0],acc[i][2+j]); acc[i][2+j]=MFMA(aF[i][1],bF1[j][1],acc[i][2+j]); } \
  __builtin_amdgcn_s_setprio(0); \
  BAR(); \
  /* q2: read A-half1 (m4..7); stage A0(t+2) */ \
  _Pragma("unroll") for (int i=0;i<4;++i){ aF[i][0]=LDA(d_,1,i,sw0); aF[i][1]=LDA(d_,1,i,sw1); } \
  if (SA0) ST_A((tc)+2, 0); \
  BAR(); \
  __builtin_amdgcn_s_setprio(1); \
  _Pragma("unroll") for (int i=0;i<4;++i) _Pragma("unroll") for (int j=0;j<2;++j){ \
    acc[4+i][j]=MFMA(aF[i][0],bF0[j][0],acc[4+i][j]); acc[4+i][j]=MFMA(aF[i][1],bF0[j][1],acc[4+i][j]); } \
  __builtin_amdgcn_s_setprio(0); \
  BAR(); \
  /* q3: stage B0(t+2); MFMA m4..7 x n2..3; counted vmcnt at tile boundary */ \
  if (SB0) ST_B((tc)+2, 0); \
  BAR(); \
  __builtin_amdgcn_s_setprio(1); \
  _Pragma("unroll") for (int i=0;i<4;++i) _Pragma("unroll") for (int j=0;j<2;++j){ \
    acc[4+i][2+j]=MFMA(aF[i][0],bF1[j][0],acc[4+i][2+j]); acc[4+i][2+j]=MFMA(aF[i][1],bF1[j][1],acc[4+i][2+j]); } \
  __builtin_amdgcn_s_setprio(0); \
  if ((VMN)==4) asm volatile("s_waitcnt vmcnt(4)" ::: "memory"); \
  else if ((VMN)==0) asm volatile("s_waitcnt vmcnt(0)" ::: "memory"); \
  BAR(); \
} while(0)

__global__ __launch_bounds__(512, 2) void gemm_kernel(
    const unsigned short* __restrict__ A, const unsigned short* __restrict__ W,
    const float* __restrict__ bias, _Float16* __restrict__ C){
  __shared__ unsigned short smem[65536];   // 128 KiB: A [0,32768), B [32768,65536)
  const int tid  = threadIdx.x;
  const int lane = tid & 63;
  const int wave = tid >> 6;
  const int l16  = lane & 15;
  const int quad = lane >> 4;
  const int wm = wave >> 2;      // 0..1 (M)
  const int wn = wave & 3;       // 0..3 (N)
  const int lrow = lane >> 3;    // 0..7
  const int lcol = lane & 7;     // 0..7

  // XCD-bijective chunked swizzle (768 = 8 xcd * 96); m-major / n-inner per chunk
  const int bid = blockIdx.x;
  const int wg = (bid & 7) * 96 + (bid >> 3);
  const int mt = wg / 6;
  const int nt = wg % 6;
  const int m0 = mt * 256;
  const int n0 = nt * 256;
  const int bb = m0 / T_;               // tile fully inside one batch (256 | 4096)
  const int act = n0 >> 9;              // 0=z(tanh), 1=f(sigm), 2=o(sigm)

  // staging: lane writes LDS linearly (row = wave*8+lrow, slot = lcol);
  // source slot pre-swizzled so LDS physSlot p holds logical p^(row&7)
  const unsigned short* aSrc = A + (int64_t)(m0 + bb + wave*8 + lrow)*IN_ + (lcol ^ lrow)*8;
  const unsigned short* bSrc = W + (int64_t)(n0 + wave*8 + lrow)*KD + (lcol ^ lrow)*8;
  const int dstBase = (wave*8 + lrow)*64 + lcol*8;   // shorts; == lane*16B per wave

  // ds_read bases (shorts); fragment row&7 == l16&7
  const int sw0 = ( quad      ^ (l16 & 7)) * 8;      // k-substep s=0
  const int sw1 = ((4 ^ quad) ^ (l16 & 7)) * 8;      // k-substep s=1
  const int aRd = (wm*64 + l16)*64;
  const int bRd = 32768 + (wn*32 + l16)*64;

  floatx4 acc[8][4];
  #pragma unroll
  for (int i=0;i<8;i++)
    #pragma unroll
    for (int j=0;j<4;j++) acc[i][j] = (floatx4){0.f,0.f,0.f,0.f};
  short8 aF[4][2], bF0[2][2], bF1[2][2];

  // prologue: tile0 {A0,B0,A1,B1} + tile1 {A0,B0}; allow last 2 half-tiles in flight
  ST_A(0,0); ST_B(0,0); ST_A(0,1); ST_B(0,1); ST_A(1,0); ST_B(1,0);
  asm volatile("s_waitcnt vmcnt(4)" ::: "memory");
  BAR();

  #pragma unroll 2
  for (int t = 0; t < NT-2; ++t){
    TILE(t, 1, 1, 1, 1, 4);
  }
  TILE(NT-2, 1, 1, 0, 0, 0);
  TILE(NT-1, 0, 0, 0, 0, -1);

  // epilogue: bias + activation, f16 store (C/D map: row=quad*4+r, col=l16)
  float bv[4];
  #pragma unroll
  for (int n=0;n<4;++n){
    const int cb = ((n&2)?128:0) + wn*32 + (n&1)*16;
    bv[n] = bias[n0 + cb + l16];
  }
  #pragma unroll
  for (int m=0;m<8;++m){
    const int rb = ((m&4)?128:0) + wm*64 + (m&3)*16;
    const int row = m0 + rb + quad*4;
    #pragma unroll
    for (int n=0;n<4;++n){
      const int cb = ((n&2)?128:0) + wn*32 + (n&1)*16;
      const int col = n0 + cb + l16;
      _Float16* cp = C + (int64_t)row*N3H + col;
      #pragma unroll
      for (int r=0;r<4;++r){
        float v = acc[m][n][r] + bv[n];
        v = (act == 0) ? tanhf_(v) : sigm(v);
        cp[(int64_t)r*N3H] = (_Float16)v;
      }
    }
  }
}

// phase 1: per-chunk affine composition (Aa, Bb): h_out = Aa*h_in + Bb
// (R1-verbatim)
__global__ void scan_phase1(const _Float16* __restrict__ conv,
                            float* __restrict__ carA, float* __restrict__ carB){
  int q = blockIdx.x*256 + threadIdx.x;     // CHUNKS*8*128 = 65536
  int chg = q & 127;
  int bq = (q >> 7) & 7;
  int c  = q >> 10;
  int ch = chg*4;
  f4 Aa = {1.f,1.f,1.f,1.f}, Bb = {0.f,0.f,0.f,0.f};
  const _Float16* p = conv + ((int64_t)bq*T_ + c*CLEN)*N3H + ch;
  for (int g=0; g<CLEN/8; ++g){
    h4 zb[8], fb[8];
    #pragma unroll
    for (int u=0;u<8;++u){
      zb[u] = *(const h4*)(p + (int64_t)u*N3H);
      fb[u] = *(const h4*)(p + (int64_t)u*N3H + 512);
    }
    #pragma unroll
    for (int u=0;u<8;++u){
      #pragma unroll
      for (int v=0;v<4;++v){
        float fv = (float)fb[u][v];
        float zv = (float)zb[u][v];
        Aa[v] *= fv;
        Bb[v] = fv*Bb[v] + (1.f-fv)*zv;
      }
    }
    p += (int64_t)8*N3H;
  }
  *(f4*)(carA + (int64_t)q*4) = Aa;
  *(f4*)(carB + (int64_t)q*4) = Bb;
}

// phase 3 with inline chunk-scan (replaces phase2 + hstart round-trip):
// each thread scans carA/carB[0..c) for its own channels (2 MB arrays, L2/L3
// hot after phase1; batched 8-ahead). Same FMA expression/order as old p2 ->
// identical numerics. Blocks with c==63 also emit hT (h0/h1 outputs).
template<int LAYER>
__global__ void scan_phase3(const _Float16* __restrict__ conv,
                            const float* __restrict__ carA, const float* __restrict__ carB,
                            float* __restrict__ hT,
                            unsigned short* __restrict__ xpad, float* __restrict__ outf){
  int q = blockIdx.x*256 + threadIdx.x;     // 65536
  int chg = q & 127;
  int bq = (q >> 7) & 7;
  int c  = q >> 10;                          // uniform per block (256 | 1024)
  int ch = chg*4;
  const int base = bq*128 + chg;             // f4 index within a 1024-f4 chunk row

  // ---- inline scan: h = hstart for chunk c (scan chunks 0..c-1) ----
  f4 h = {0.f,0.f,0.f,0.f};
  {
    int j = 0;
    for (; j+8 <= c; j += 8){
      f4 a[8], b[8];
      #pragma unroll
      for (int u=0;u<8;++u){
        a[u] = *(const f4*)(carA + (int64_t)((j+u)*1024 + base)*4);
        b[u] = *(const f4*)(carB + (int64_t)((j+u)*1024 + base)*4);
      }
      #pragma unroll
      for (int u=0;u<8;++u)
        #pragma unroll
        for (int v=0;v<4;++v) h[v] = a[u][v]*h[v] + b[u][v];
    }
    for (; j < c; ++j){
      f4 a = *(const f4*)(carA + (int64_t)(j*1024 + base)*4);
      f4 b = *(const f4*)(carB + (int64_t)(j*1024 + base)*4);
      #pragma unroll
      for (int v=0;v<4;++v) h[v] = a[v]*h[v] + b[v];
    }
  }
  if (c == CHUNKS-1){
    // final carry: apply chunk 63's own (A,B) -> hT (4096 channels, unique)
    f4 a = *(const f4*)(carA + (int64_t)((CHUNKS-1)*1024 + base)*4);
    f4 b = *(const f4*)(carB + (int64_t)((CHUNKS-1)*1024 + base)*4);
    #pragma unroll
    for (int v=0;v<4;++v) hT[bq*512 + ch + v] = a[v]*h[v] + b[v];
  }

  // ---- replay chunk with true h-start, apply o*h (R1-verbatim body) ----
  const _Float16* p = conv + ((int64_t)bq*T_ + c*CLEN)*N3H + ch;
  int t = c*CLEN;
  for (int g=0; g<CLEN/8; ++g){
    h4 zb[8], fb[8], ob[8];
    #pragma unroll
    for (int u=0;u<8;++u){
      zb[u] = *(const h4*)(p + (int64_t)u*N3H);
      fb[u] = *(const h4*)(p + (int64_t)u*N3H + 512);
      ob[u] = *(const h4*)(p + (int64_t)u*N3H + 1024);
    }
    #pragma unroll
    for (int u=0;u<8;++u){
      if (LAYER == 0){
        us4 ov4;
        #pragma unroll
        for (int v=0;v<4;++v){
          float fv = (float)fb[u][v];
          h[v] = fv*h[v] + (1.f-fv)*(float)zb[u][v];
          ov4[v] = f2bf((float)ob[u][v]*h[v]);
        }
        *(us4*)(xpad + ((int64_t)bq*TP1 + t+u + 1)*IN_ + ch) = ov4;
      } else {
        f4 of4;
        #pragma unroll
        for (int v=0;v<4;++v){
          float fv = (float)fb[u][v];
          h[v] = fv*h[v] + (1.f-fv)*(float)zb[u][v];
          of4[v] = (float)ob[u][v]*h[v];
        }
        *(f4*)(outf + ((int64_t)bq*T_ + t+u)*H_ + ch) = of4;
      }
    }
    t += 8; p += (int64_t)8*N3H;
  }
}

extern "C" void kernel_launch(void* const* d_in, const int* in_sizes, int n_in,
                              void* d_out, int out_size, void* d_ws, size_t ws_size,
                              hipStream_t stream){
  const float* x  = (const float*)d_in[0];
  const float* w0 = (const float*)d_in[1];
  const float* b0 = (const float*)d_in[2];
  const float* w1 = (const float*)d_in[3];
  const float* b1 = (const float*)d_in[4];
  float* out = (float*)d_out;

  char* ws = (char*)d_ws;
  size_t off = 0;
  auto alloc = [&](size_t bytes)->char*{
    char* p = ws + off; off = (off + bytes + 255) & ~(size_t)255; return p; };
  unsigned short* xpad = (unsigned short*)alloc((size_t)B_*TP1*IN_*2);
  unsigned short* Wt0  = (unsigned short*)alloc((size_t)N3H*KD*2);
  unsigned short* Wt1  = (unsigned short*)alloc((size_t)N3H*KD*2);
  _Float16* conv = (_Float16*)alloc((size_t)B_*T_*N3H*2);
  float* carA = (float*)alloc((size_t)CHUNKS*4096*4);
  float* carB = (float*)alloc((size_t)CHUNKS*4096*4);
  if (off > ws_size) return;  // workspace too small -> fail loudly in validation

  float* out_main = out;
  float* h0 = out + (int64_t)B_*T_*H_;
  float* h1 = h0 + B_*H_;

  // prep: cast_pad + both weight transposes in one launch
  const int64_t castN = (int64_t)B_*TP1*(IN_/4);
  const int64_t prepN = castN + (int64_t)2*N3H*512;
  prep_kernel<<<(int)((prepN + 255)/256), 256, 0, stream>>>(x, xpad, w0, Wt0, w1, Wt1);

  const int ggrid = ((B_*T_)/256) * (N3H/256);   // 128*6 = 768
  const int sgrid = (CHUNKS*8*128) / 256;        // 256
  gemm_kernel<<<ggrid, 512, 0, stream>>>(xpad, Wt0, b0, conv);
  scan_phase1<<<sgrid, 256, 0, stream>>>(conv, carA, carB);
  scan_phase3<0><<<sgrid, 256, 0, stream>>>(conv, carA, carB, h0, xpad, nullptr);

  gemm_kernel<<<ggrid, 512, 0, stream>>>(xpad, Wt1, b1, conv);
  scan_phase1<<<sgrid, 256, 0, stream>>>(conv, carA, carB);
  scan_phase3<1><<<sgrid, 256, 0, stream>>>(conv, carA, carB, h1, nullptr, out_main);
}